// Round 10
// baseline (76.944 us; speedup 1.0000x reference)
//
#include <hip/hip_runtime.h>

constexpr int IN_DIM  = 4 * 64 * 64;   // 16384
constexpr int OUT_CH  = 2;
constexpr int BLOCK   = 512;
constexpr int NGROUPS = IN_DIM / 4;        // 4096 16B groups per sample
constexpr int ITERS   = NGROUPS / BLOCK;   // 8 per thread

typedef float fx4 __attribute__((ext_vector_type(4)));

// Single fused kernel: one sample per 512-thread block.
//  - x: non-temporal loads (streaming, keep L2 for W)
//  - W: plain fp32 loads (6.25 MiB total, L2/L3-resident; exact math)
//  - deep prefetch: all 24 loads issued back-to-back into registers
//  - wave-contiguous ordering: each wave covers a contiguous 8 KiB of the row
__global__ __launch_bounds__(BLOCK) void dot_fused_kernel(
    const float* __restrict__ x,     // [B, IN_DIM] fp32
    const int*   __restrict__ t,     // [B]
    const float* __restrict__ W,     // [NT, 2, IN_DIM] fp32
    const float* __restrict__ bias,  // [NT, 2] fp32
    float*       __restrict__ out)   // [B, 2]
{
    const int b    = blockIdx.x;
    const int tid  = threadIdx.x;
    const int wave = tid >> 6;
    const int lane = tid & 63;
    // wave w owns groups [w*512, (w+1)*512): its 8 loads are contiguous 1 KiB lines
    const int g0   = wave * (ITERS * 64) + lane;

    const fx4* xv = reinterpret_cast<const fx4*>(x + (size_t)b * IN_DIM);

    // issue streaming x loads first (no dependency on t[b])
    fx4 xr[ITERS];
#pragma unroll
    for (int i = 0; i < ITERS; ++i)
        xr[i] = __builtin_nontemporal_load(&xv[g0 + i * 64]);

    const int idx = (980 - t[b]) / 20;
    const fx4* w0 = reinterpret_cast<const fx4*>(W + (size_t)idx * OUT_CH * IN_DIM);
    const fx4* w1 = w0 + NGROUPS;

    fx4 w0r[ITERS], w1r[ITERS];
#pragma unroll
    for (int i = 0; i < ITERS; ++i) w0r[i] = w0[g0 + i * 64];
#pragma unroll
    for (int i = 0; i < ITERS; ++i) w1r[i] = w1[g0 + i * 64];

    float e0 = 0.0f, e1 = 0.0f, o0 = 0.0f, o1 = 0.0f;
#pragma unroll
    for (int i = 0; i < ITERS; i += 2) {
        const fx4 xa = xr[i], xb = xr[i + 1];
        e0 += xa.x * w0r[i].x + xa.y * w0r[i].y + xa.z * w0r[i].z + xa.w * w0r[i].w;
        e1 += xa.x * w1r[i].x + xa.y * w1r[i].y + xa.z * w1r[i].z + xa.w * w1r[i].w;
        o0 += xb.x * w0r[i+1].x + xb.y * w0r[i+1].y + xb.z * w0r[i+1].z + xb.w * w0r[i+1].w;
        o1 += xb.x * w1r[i+1].x + xb.y * w1r[i+1].y + xb.z * w1r[i+1].z + xb.w * w1r[i+1].w;
    }
    float acc0 = e0 + o0;
    float acc1 = e1 + o1;

    for (int off = 32; off > 0; off >>= 1) {
        acc0 += __shfl_down(acc0, off, 64);
        acc1 += __shfl_down(acc1, off, 64);
    }

    __shared__ float red[BLOCK / 64][2];
    if (lane == 0) {
        red[wave][0] = acc0;
        red[wave][1] = acc1;
    }
    __syncthreads();

    if (tid == 0) {
        float s0 = 0.0f, s1 = 0.0f;
#pragma unroll
        for (int w = 0; w < BLOCK / 64; ++w) { s0 += red[w][0]; s1 += red[w][1]; }
        out[(size_t)b * OUT_CH + 0] = s0 + bias[idx * OUT_CH + 0];
        out[(size_t)b * OUT_CH + 1] = s1 + bias[idx * OUT_CH + 1];
    }
}

extern "C" void kernel_launch(void* const* d_in, const int* in_sizes, int n_in,
                              void* d_out, int out_size, void* d_ws, size_t ws_size,
                              hipStream_t stream) {
    const float* x    = (const float*)d_in[0];
    const int*   t    = (const int*)d_in[1];
    const float* W    = (const float*)d_in[2];
    const float* bias = (const float*)d_in[3];
    float*       out  = (float*)d_out;
    const int B = in_sizes[1];  // 4096

    dot_fused_kernel<<<B, BLOCK, 0, stream>>>(x, t, W, bias, out);
}

// Round 11
// 58.113 us; speedup vs baseline: 1.3240x; 1.3240x over previous
//
#include <hip/hip_runtime.h>

constexpr int IN_DIM  = 4 * 64 * 64;   // 16384
constexpr int OUT_CH  = 2;
constexpr int NT      = 50;
constexpr int BLOCK   = 512;
constexpr int NGROUPS = IN_DIM / 4;        // 4096 16B groups per sample
constexpr int ITERS   = NGROUPS / BLOCK;   // 8 per thread
constexpr size_t WB_BYTES = (size_t)NT * OUT_CH * IN_DIM * 2;  // 3.125 MiB bf16

typedef float fx4 __attribute__((ext_vector_type(4)));

__device__ __forceinline__ unsigned short f2bf_rn(float f) {
    unsigned int u = __float_as_uint(f);
    u += 0x7FFFu + ((u >> 16) & 1u);   // round-to-nearest-even
    return (unsigned short)(u >> 16);
}

// Repack W [NT][2][IN_DIM] fp32 -> bf16, channel-interleaved per 4-element group:
// one uint4 = {ch0 e0..e3, ch1 e0..e3} as 8 bf16. 3.125 MiB -> fits per-XCD L2
// (load-bearing: fp32 W thrashes L2, r10 regressed 58->77 µs).
__global__ __launch_bounds__(256) void convert_w_kernel(
    const float* __restrict__ W, unsigned short* __restrict__ Wb)
{
    const int g0 = (blockIdx.x * 256 + threadIdx.x) * 2;
    if (g0 >= NT * NGROUPS) return;
#pragma unroll
    for (int k = 0; k < 2; ++k) {
        const int g  = g0 + k;
        const int ts = g / NGROUPS;
        const int j  = g - ts * NGROUPS;
        const float* base = W + (size_t)ts * OUT_CH * IN_DIM;
        const fx4 a = __builtin_nontemporal_load(reinterpret_cast<const fx4*>(base + j * 4));
        const fx4 c = __builtin_nontemporal_load(reinterpret_cast<const fx4*>(base + IN_DIM + j * 4));
        ushort4 lo, hi;
        lo.x = f2bf_rn(a.x); lo.y = f2bf_rn(a.y); lo.z = f2bf_rn(a.z); lo.w = f2bf_rn(a.w);
        hi.x = f2bf_rn(c.x); hi.y = f2bf_rn(c.y); hi.z = f2bf_rn(c.z); hi.w = f2bf_rn(c.w);
        ushort4* dst = reinterpret_cast<ushort4*>(Wb + (size_t)ts * OUT_CH * IN_DIM) + (size_t)j * 2;
        dst[0] = lo;
        dst[1] = hi;
    }
}

// One sample per 512-thread block (round-8 structure, best measured: 58.1 µs).
//  - x: non-temporal (keeps bf16 W pack L2-resident; r9 showed removing nt
//    costs +7 µs)
//  - deep prefetch: all 8 nt x + 8 W loads issued back-to-back into registers
__global__ __launch_bounds__(BLOCK) void dot_bf16w_kernel(
    const float* __restrict__ x,             // [B, IN_DIM] fp32
    const int*   __restrict__ t,             // [B]
    const unsigned short* __restrict__ Wb,   // packed bf16 weights
    const float* __restrict__ bias,          // [NT, 2] fp32
    float*       __restrict__ out)           // [B, 2]
{
    const int b   = blockIdx.x;
    const int tid = threadIdx.x;

    const fx4* xv = reinterpret_cast<const fx4*>(x + (size_t)b * IN_DIM);

    // issue the streaming x loads first (no dependency on t[b])
    fx4 xr[ITERS];
#pragma unroll
    for (int i = 0; i < ITERS; ++i)
        xr[i] = __builtin_nontemporal_load(&xv[tid + i * BLOCK]);

    const int idx = (980 - t[b]) / 20;
    const uint4* wv = reinterpret_cast<const uint4*>(Wb + (size_t)idx * OUT_CH * IN_DIM);

    uint4 wr[ITERS];
#pragma unroll
    for (int i = 0; i < ITERS; ++i)
        wr[i] = wv[tid + i * BLOCK];

    float e0 = 0.0f, e1 = 0.0f, o0 = 0.0f, o1 = 0.0f;
#pragma unroll
    for (int i = 0; i < ITERS; i += 2) {
        const fx4  xa = xr[i],     xb = xr[i + 1];
        const uint4 wa = wr[i],    wb = wr[i + 1];

        e0 += xa.x * __uint_as_float(wa.x << 16)
            + xa.y * __uint_as_float(wa.x & 0xFFFF0000u)
            + xa.z * __uint_as_float(wa.y << 16)
            + xa.w * __uint_as_float(wa.y & 0xFFFF0000u);
        e1 += xa.x * __uint_as_float(wa.z << 16)
            + xa.y * __uint_as_float(wa.z & 0xFFFF0000u)
            + xa.z * __uint_as_float(wa.w << 16)
            + xa.w * __uint_as_float(wa.w & 0xFFFF0000u);

        o0 += xb.x * __uint_as_float(wb.x << 16)
            + xb.y * __uint_as_float(wb.x & 0xFFFF0000u)
            + xb.z * __uint_as_float(wb.y << 16)
            + xb.w * __uint_as_float(wb.y & 0xFFFF0000u);
        o1 += xb.x * __uint_as_float(wb.z << 16)
            + xb.y * __uint_as_float(wb.z & 0xFFFF0000u)
            + xb.z * __uint_as_float(wb.w << 16)
            + xb.w * __uint_as_float(wb.w & 0xFFFF0000u);
    }
    float acc0 = e0 + o0;
    float acc1 = e1 + o1;

    for (int off = 32; off > 0; off >>= 1) {
        acc0 += __shfl_down(acc0, off, 64);
        acc1 += __shfl_down(acc1, off, 64);
    }

    __shared__ float red[BLOCK / 64][2];
    const int wave = tid >> 6;
    if ((tid & 63) == 0) {
        red[wave][0] = acc0;
        red[wave][1] = acc1;
    }
    __syncthreads();

    if (tid == 0) {
        float s0 = 0.0f, s1 = 0.0f;
#pragma unroll
        for (int w = 0; w < BLOCK / 64; ++w) { s0 += red[w][0]; s1 += red[w][1]; }
        out[(size_t)b * OUT_CH + 0] = s0 + bias[idx * OUT_CH + 0];
        out[(size_t)b * OUT_CH + 1] = s1 + bias[idx * OUT_CH + 1];
    }
}

// Fallback (round-1 fp32 path) if d_ws is too small for the bf16 W copy.
__global__ __launch_bounds__(256) void dot_f32_kernel(
    const float* __restrict__ x, const int* __restrict__ t,
    const float* __restrict__ W, const float* __restrict__ bias,
    float* __restrict__ out)
{
    const int b   = blockIdx.x;
    const int tid = threadIdx.x;
    const int idx = (980 - t[b]) / 20;

    const float4* xv = reinterpret_cast<const float4*>(x + (size_t)b * IN_DIM);
    const float4* w0 = reinterpret_cast<const float4*>(W + (size_t)idx * OUT_CH * IN_DIM);
    const float4* w1 = w0 + IN_DIM / 4;

    float acc0 = 0.0f, acc1 = 0.0f;
#pragma unroll
    for (int i = 0; i < 16; ++i) {
        const int j = tid + i * 256;
        const float4 xv4 = xv[j];
        const float4 a   = w0[j];
        const float4 c   = w1[j];
        acc0 += xv4.x * a.x + xv4.y * a.y + xv4.z * a.z + xv4.w * a.w;
        acc1 += xv4.x * c.x + xv4.y * c.y + xv4.z * c.z + xv4.w * c.w;
    }
    for (int off = 32; off > 0; off >>= 1) {
        acc0 += __shfl_down(acc0, off, 64);
        acc1 += __shfl_down(acc1, off, 64);
    }
    __shared__ float red[4][2];
    const int wave = tid >> 6;
    if ((tid & 63) == 0) { red[wave][0] = acc0; red[wave][1] = acc1; }
    __syncthreads();
    if (tid == 0) {
        float s0 = red[0][0] + red[1][0] + red[2][0] + red[3][0];
        float s1 = red[0][1] + red[1][1] + red[2][1] + red[3][1];
        out[(size_t)b * OUT_CH + 0] = s0 + bias[idx * OUT_CH + 0];
        out[(size_t)b * OUT_CH + 1] = s1 + bias[idx * OUT_CH + 1];
    }
}

extern "C" void kernel_launch(void* const* d_in, const int* in_sizes, int n_in,
                              void* d_out, int out_size, void* d_ws, size_t ws_size,
                              hipStream_t stream) {
    const float* x    = (const float*)d_in[0];
    const int*   t    = (const int*)d_in[1];
    const float* W    = (const float*)d_in[2];
    const float* bias = (const float*)d_in[3];
    float*       out  = (float*)d_out;
    const int B = in_sizes[1];  // 4096

    if (ws_size >= WB_BYTES) {
        unsigned short* Wb = (unsigned short*)d_ws;
        const int nthreads = NT * NGROUPS / 2;
        convert_w_kernel<<<(nthreads + 255) / 256, 256, 0, stream>>>(W, Wb);
        dot_bf16w_kernel<<<B, BLOCK, 0, stream>>>(x, t, Wb, bias, out);
    } else {
        dot_f32_kernel<<<B, 256, 0, stream>>>(x, t, W, bias, out);
    }
}